// Round 6
// baseline (152.049 us; speedup 1.0000x reference)
//
#include <hip/hip_runtime.h>
#include <hip/hip_fp16.h>
#include <math.h>

namespace {
constexpr int kN = 16, kC = 64, kH = 224, kW = 224;
constexpr int kOH = kH / 2, kOW = kW / 2;          // 112 x 112
constexpr int R_OUT = 8;                           // output rows per block
constexpr int BAND_ROWS = 2 * R_OUT + 6;           // 22 lo/hi rows (halo 3 each side)
constexpr int NBANDS = kOH / R_OUT;                // 14
constexpr int PADW = kW + 4;                       // row pad (bank spread); 912B rows
constexpr int kGrid = kN * kC * NBANDS;            // 14336 (multiple of 8)
constexpr int kChunk = kGrid / 8;                  // 1792 blocks per XCD
constexpr float kMagBias = 0.01f;
constexpr float kMB2 = kMagBias * kMagBias;
constexpr float kSqrtHalf = 0.70710678118654752f;

// Horizontal taps (plain).
constexpr float H0[5] = {-0.05f, 0.25f, 0.6f, 0.25f, -0.05f};
constexpr float H1[7] = {-0.0107142857142857f, 0.0535714285714286f,
                          0.2607142857142857f, -0.6071428571428571f,
                          0.2607142857142857f, 0.0535714285714286f,
                         -0.0107142857142857f};
// Vertical taps with sqrt(1/2) folded in (q2c scale) — used for lh/hh (H1S)
// and hl (H0S). ll keeps plain H0 (pooled LL is unscaled).
constexpr float H1S[7] = {H1[0] * kSqrtHalf, H1[1] * kSqrtHalf, H1[2] * kSqrtHalf,
                          H1[3] * kSqrtHalf, H1[4] * kSqrtHalf, H1[5] * kSqrtHalf,
                          H1[6] * kSqrtHalf};
constexpr float H0S[5] = {H0[0] * kSqrtHalf, H0[1] * kSqrtHalf, H0[2] * kSqrtHalf,
                          H0[3] * kSqrtHalf, H0[4] * kSqrtHalf};
}  // namespace

typedef float v4f __attribute__((ext_vector_type(4)));

__device__ __forceinline__ float magf(float re, float im) {
    return __builtin_amdgcn_sqrtf(fmaf(re, re, fmaf(im, im, kMB2))) - kMagBias;
}

__device__ __forceinline__ void unpack2(unsigned u, float& a, float& b) {
    const __half2 h = __builtin_bit_cast(__half2, u);
    a = __low2float(h);
    b = __high2float(h);
}

__device__ __forceinline__ void nt_store4(float* p, float a, float b, float c, float d) {
    v4f v; v.x = a; v.y = b; v.z = c; v.w = d;
    __builtin_nontemporal_store(v, reinterpret_cast<v4f*>(p));
}

struct Acc {
    float lh_a, lh_b, lh_c, lh_d;
    float hh_a, hh_b, hh_c, hh_d;
    float ll_a, ll_b, ll_c, ll_d;
    float hl_a, hl_b, hl_c, hl_d;
};

__device__ __forceinline__ void acc_init(Acc& A) {
    A.lh_a = A.lh_b = A.lh_c = A.lh_d = 0.f;
    A.hh_a = A.hh_b = A.hh_c = A.hh_d = 0.f;
    A.ll_a = A.ll_b = A.ll_c = A.ll_d = 0.f;
    A.hl_a = A.hl_b = A.hl_c = A.hl_d = 0.f;
}

// One window-row step; k is a compile-time unroll index so guards/taps fold.
__device__ __forceinline__ void acc_step(Acc& A, int k, float lo0, float hi0,
                                         float lo1, float hi1) {
    if (k <= 6) {                 // 7-tap, even output row (taps H1S[k])
        A.lh_a = fmaf(H1S[k], lo0, A.lh_a);
        A.lh_b = fmaf(H1S[k], lo1, A.lh_b);
        A.hh_a = fmaf(H1S[k], hi0, A.hh_a);
        A.hh_b = fmaf(H1S[k], hi1, A.hh_b);
    }
    if (k >= 1) {                 // 7-tap, odd output row (taps H1S[k-1])
        A.lh_c = fmaf(H1S[k - 1], lo0, A.lh_c);
        A.lh_d = fmaf(H1S[k - 1], lo1, A.lh_d);
        A.hh_c = fmaf(H1S[k - 1], hi0, A.hh_c);
        A.hh_d = fmaf(H1S[k - 1], hi1, A.hh_d);
    }
    if (k >= 1 && k <= 5) {       // 5-tap, even output row
        A.ll_a = fmaf(H0[k - 1], lo0, A.ll_a);
        A.ll_b = fmaf(H0[k - 1], lo1, A.ll_b);
        A.hl_a = fmaf(H0S[k - 1], hi0, A.hl_a);
        A.hl_b = fmaf(H0S[k - 1], hi1, A.hl_b);
    }
    if (k >= 2 && k <= 6) {       // 5-tap, odd output row
        A.ll_c = fmaf(H0[k - 2], lo0, A.ll_c);
        A.ll_d = fmaf(H0[k - 2], lo1, A.ll_d);
        A.hl_c = fmaf(H0S[k - 2], hi0, A.hl_c);
        A.hl_d = fmaf(H0S[k - 2], hi1, A.hl_d);
    }
}

__global__ __launch_bounds__(256, 8)
void scat_fused_kernel(const float* __restrict__ x, float* __restrict__ out) {
    // Packed horizontal filter outputs: per (row, col) a __half2 {lo, hi}.
    __shared__ __half2 sLH[BAND_ROWS][PADW];       // 22*228*4 = 20,064 B -> 8 blocks/CU

    // XCD-aware bijective swizzle: adjacent logical bands share an XCD's L2.
    const int phys = blockIdx.x;
    const int b    = (phys & 7) * kChunk + (phys >> 3);

    const int band = b % NBANDS;
    const int ch   = b / NBANDS;                   // n*kC + c
    const int i0   = band * R_OUT;                 // first output row of band
    const int rbase = 2 * i0 - 3;                  // first lo/hi image row (may be <0)
    const int tid  = threadIdx.x;

    const float* __restrict__ xp = x + (size_t)ch * (kH * kW);

    // ---------------- Phase 1: horizontal lo/hi -> LDS (packed fp16) ----------------
    // Tasks: 22 rows x 28 col-groups of 8 output cols; exactly 4 float4 loads each
    // (window cols c0-3..c0+10); image-edge columns via register mirror-selects.
    for (int task = tid; task < BAND_ROWS * 28; task += 256) {
        const int s  = task / 28;
        const int cg = task - s * 28;
        int r = rbase + s;
        r = (r < 0) ? (-1 - r) : ((r > kH - 1) ? (2 * kH - 1 - r) : r);
        const float* __restrict__ rowp = xp + r * kW;
        const int c0 = cg * 8;

        const float4 A  = *reinterpret_cast<const float4*>(rowp + (cg ? c0 - 4 : 0));
        const float4 B  = *reinterpret_cast<const float4*>(rowp + c0);
        const float4 Cv = *reinterpret_cast<const float4*>(rowp + c0 + 4);
        const float4 D  = *reinterpret_cast<const float4*>(rowp + (cg < 27 ? c0 + 8 : kW - 16));

        float xv[14];  // cols c0-3 .. c0+10
        xv[0]  = cg ? A.y : B.z;          // col -3 -> 2 at left edge
        xv[1]  = cg ? A.z : B.y;          // col -2 -> 1
        xv[2]  = cg ? A.w : B.x;          // col -1 -> 0
        xv[3]  = B.x;  xv[4] = B.y;  xv[5] = B.z;  xv[6] = B.w;
        xv[7]  = Cv.x; xv[8] = Cv.y; xv[9] = Cv.z; xv[10] = Cv.w;
        xv[11] = (cg < 27) ? D.x : Cv.w;  // col 224 -> 223 at right edge
        xv[12] = (cg < 27) ? D.y : Cv.z;  // col 225 -> 222
        xv[13] = (cg < 27) ? D.z : Cv.y;  // col 226 -> 221

        unsigned int pk[8];
        #pragma unroll
        for (int u = 0; u < 8; ++u) {
            const float lo = H0[0] * xv[u + 1] + H0[1] * xv[u + 2] + H0[2] * xv[u + 3]
                           + H0[3] * xv[u + 4] + H0[4] * xv[u + 5];
            const float hi = H1[0] * xv[u + 0] + H1[1] * xv[u + 1] + H1[2] * xv[u + 2]
                           + H1[3] * xv[u + 3] + H1[4] * xv[u + 4] + H1[5] * xv[u + 5]
                           + H1[6] * xv[u + 6];
            __half2 p = __floats2half2_rn(lo, hi);
            pk[u] = __builtin_bit_cast(unsigned int, p);
        }
        *reinterpret_cast<uint4*>(&sLH[s][c0])     = make_uint4(pk[0], pk[1], pk[2], pk[3]);
        *reinterpret_cast<uint4*>(&sLH[s][c0 + 4]) = make_uint4(pk[4], pk[5], pk[6], pk[7]);
    }
    __syncthreads();

    // ---------------- Phase 2: 4 output pixels per thread, single pass ----------------
    const int n = ch / kC;
    const int c = ch - n * kC;
    const size_t plane   = (size_t)kOH * kOW;      // 12544
    const size_t ostride = (size_t)kC * plane;     // orientation stride in output
    float* __restrict__ outp = out + ((size_t)n * 7 * kC + c) * plane;

    // Tasks: 8 rows x 28 quad-pixel groups = 224 (single uniform pass).
    if (tid < R_OUT * 28) {
        const int ii = tid / 28;                   // 0..7
        const int jq = tid - ii * 28;              // quad: pixels 4jq..4jq+3
        const int s1 = 2 * ii + 3;                 // LDS row of image row 2*(i0+ii)

        float rA[7], rB[7], rC[7], rD[7];          // per-plane results, 4 pixels

        #pragma unroll
        for (int half = 0; half < 2; ++half) {
            Acc A0, A1;
            acc_init(A0);
            acc_init(A1);
            #pragma unroll
            for (int k = 0; k < 8; ++k) {
                const uint4 w4 = *reinterpret_cast<const uint4*>(
                    &sLH[s1 - 3 + k][8 * jq + 4 * half]);
                float lo00, hi00, lo01, hi01, lo10, hi10, lo11, hi11;
                unpack2(w4.x, lo00, hi00);
                unpack2(w4.y, lo01, hi01);
                unpack2(w4.z, lo10, hi10);
                unpack2(w4.w, lo11, hi11);
                acc_step(A0, k, lo00, hi00, lo01, hi01);
                acc_step(A1, k, lo10, hi10, lo11, hi11);
            }
            float* r0 = half ? rC : rA;
            float* r1 = half ? rD : rB;
            r0[0] = fmaxf(fmaxf(A0.ll_a, A0.ll_b), fmaxf(A0.ll_c, A0.ll_d));
            r1[0] = fmaxf(fmaxf(A1.ll_a, A1.ll_b), fmaxf(A1.ll_c, A1.ll_d));
            // q2c magnitudes (sqrt(1/2) pre-folded into vertical taps)
            r0[1] = magf(A0.lh_a - A0.lh_d, A0.lh_b + A0.lh_c);   // 15
            r0[2] = magf(A0.hh_a - A0.hh_d, A0.hh_b + A0.hh_c);   // 45
            r0[3] = magf(A0.hl_a - A0.hl_d, A0.hl_b + A0.hl_c);   // 75
            r0[4] = magf(A0.hl_a + A0.hl_d, A0.hl_b - A0.hl_c);   // 105
            r0[5] = magf(A0.hh_a + A0.hh_d, A0.hh_b - A0.hh_c);   // 135
            r0[6] = magf(A0.lh_a + A0.lh_d, A0.lh_b - A0.lh_c);   // 165
            r1[1] = magf(A1.lh_a - A1.lh_d, A1.lh_b + A1.lh_c);
            r1[2] = magf(A1.hh_a - A1.hh_d, A1.hh_b + A1.hh_c);
            r1[3] = magf(A1.hl_a - A1.hl_d, A1.hl_b + A1.hl_c);
            r1[4] = magf(A1.hl_a + A1.hl_d, A1.hl_b - A1.hl_c);
            r1[5] = magf(A1.hh_a + A1.hh_d, A1.hh_b - A1.hh_c);
            r1[6] = magf(A1.lh_a + A1.lh_d, A1.lh_b - A1.lh_c);
        }

        // 7 x 16B nontemporal stores (write-once data, keep out of L2/L3).
        const size_t pix = (size_t)(i0 + ii) * kOW + 4 * jq;
        #pragma unroll
        for (int p = 0; p < 7; ++p) {
            nt_store4(outp + (size_t)p * ostride + pix, rA[p], rB[p], rC[p], rD[p]);
        }
    }
}

extern "C" void kernel_launch(void* const* d_in, const int* in_sizes, int n_in,
                              void* d_out, int out_size, void* d_ws, size_t ws_size,
                              hipStream_t stream) {
    const float* x = (const float*)d_in[0];
    float* out = (float*)d_out;
    scat_fused_kernel<<<kGrid, 256, 0, stream>>>(x, out);
}

// Round 7
// 112.093 us; speedup vs baseline: 1.3564x; 1.3564x over previous
//
#include <hip/hip_runtime.h>
#include <hip/hip_fp16.h>
#include <math.h>

namespace {
constexpr int kN = 16, kC = 64, kH = 224, kW = 224;
constexpr int kOH = kH / 2, kOW = kW / 2;          // 112 x 112
constexpr int R_OUT = 8;                           // output rows per block
constexpr int BAND_ROWS = 2 * R_OUT + 6;           // 22 lo/hi rows (halo 3 each side)
constexpr int NBANDS = kOH / R_OUT;                // 14
constexpr int PADW = kW + 4;                       // row pad (bank spread); 912B rows
constexpr int kGrid = kN * kC * NBANDS;            // 14336 (multiple of 8)
constexpr int kChunk = kGrid / 8;                  // 1792 blocks per XCD
constexpr float kMagBias = 0.01f;
constexpr float kMB2 = kMagBias * kMagBias;
constexpr float kSqrtHalf = 0.70710678118654752f;

// Horizontal taps (plain).
constexpr float H0[5] = {-0.05f, 0.25f, 0.6f, 0.25f, -0.05f};
constexpr float H1[7] = {-0.0107142857142857f, 0.0535714285714286f,
                          0.2607142857142857f, -0.6071428571428571f,
                          0.2607142857142857f, 0.0535714285714286f,
                         -0.0107142857142857f};
// Vertical taps with sqrt(1/2) folded in (q2c scale) — used for lh/hh (H1S)
// and hl (H0S). ll keeps plain H0 (pooled LL is unscaled).
constexpr float H1S[7] = {H1[0] * kSqrtHalf, H1[1] * kSqrtHalf, H1[2] * kSqrtHalf,
                          H1[3] * kSqrtHalf, H1[4] * kSqrtHalf, H1[5] * kSqrtHalf,
                          H1[6] * kSqrtHalf};
constexpr float H0S[5] = {H0[0] * kSqrtHalf, H0[1] * kSqrtHalf, H0[2] * kSqrtHalf,
                          H0[3] * kSqrtHalf, H0[4] * kSqrtHalf};
}  // namespace

typedef float v2f __attribute__((ext_vector_type(2)));

__device__ __forceinline__ float magf(float re, float im) {
    return __builtin_amdgcn_sqrtf(fmaf(re, re, fmaf(im, im, kMB2))) - kMagBias;
}

__device__ __forceinline__ void unpack2(unsigned u, float& a, float& b) {
    const __half2 h = __builtin_bit_cast(__half2, u);
    a = __low2float(h);
    b = __high2float(h);
}

__device__ __forceinline__ void nt_store2(float* p, float a, float b) {
    v2f v; v.x = a; v.y = b;
    __builtin_nontemporal_store(v, reinterpret_cast<v2f*>(p));
}

struct Acc {
    float lh_a, lh_b, lh_c, lh_d;
    float hh_a, hh_b, hh_c, hh_d;
    float ll_a, ll_b, ll_c, ll_d;
    float hl_a, hl_b, hl_c, hl_d;
};

__device__ __forceinline__ void acc_init(Acc& A) {
    A.lh_a = A.lh_b = A.lh_c = A.lh_d = 0.f;
    A.hh_a = A.hh_b = A.hh_c = A.hh_d = 0.f;
    A.ll_a = A.ll_b = A.ll_c = A.ll_d = 0.f;
    A.hl_a = A.hl_b = A.hl_c = A.hl_d = 0.f;
}

// One window-row step; k is a compile-time unroll index so guards/taps fold.
__device__ __forceinline__ void acc_step(Acc& A, int k, float lo0, float hi0,
                                         float lo1, float hi1) {
    if (k <= 6) {                 // 7-tap, even output row (taps H1S[k])
        A.lh_a = fmaf(H1S[k], lo0, A.lh_a);
        A.lh_b = fmaf(H1S[k], lo1, A.lh_b);
        A.hh_a = fmaf(H1S[k], hi0, A.hh_a);
        A.hh_b = fmaf(H1S[k], hi1, A.hh_b);
    }
    if (k >= 1) {                 // 7-tap, odd output row (taps H1S[k-1])
        A.lh_c = fmaf(H1S[k - 1], lo0, A.lh_c);
        A.lh_d = fmaf(H1S[k - 1], lo1, A.lh_d);
        A.hh_c = fmaf(H1S[k - 1], hi0, A.hh_c);
        A.hh_d = fmaf(H1S[k - 1], hi1, A.hh_d);
    }
    if (k >= 1 && k <= 5) {       // 5-tap, even output row
        A.ll_a = fmaf(H0[k - 1], lo0, A.ll_a);
        A.ll_b = fmaf(H0[k - 1], lo1, A.ll_b);
        A.hl_a = fmaf(H0S[k - 1], hi0, A.hl_a);
        A.hl_b = fmaf(H0S[k - 1], hi1, A.hl_b);
    }
    if (k >= 2 && k <= 6) {       // 5-tap, odd output row
        A.ll_c = fmaf(H0[k - 2], lo0, A.ll_c);
        A.ll_d = fmaf(H0[k - 2], lo1, A.ll_d);
        A.hl_c = fmaf(H0S[k - 2], hi0, A.hl_c);
        A.hl_d = fmaf(H0S[k - 2], hi1, A.hl_d);
    }
}

__global__ __launch_bounds__(256, 8)
void scat_fused_kernel(const float* __restrict__ x, float* __restrict__ out) {
    // Packed horizontal filter outputs: per (row, col) a __half2 {lo, hi}.
    __shared__ __half2 sLH[BAND_ROWS][PADW];       // 22*228*4 = 20,064 B -> 8 blocks/CU

    // XCD-aware bijective swizzle: adjacent logical bands share an XCD's L2.
    const int phys = blockIdx.x;
    const int b    = (phys & 7) * kChunk + (phys >> 3);

    const int band = b % NBANDS;
    const int ch   = b / NBANDS;                   // n*kC + c
    const int i0   = band * R_OUT;                 // first output row of band
    const int rbase = 2 * i0 - 3;                  // first lo/hi image row (may be <0)
    const int tid  = threadIdx.x;

    const float* __restrict__ xp = x + (size_t)ch * (kH * kW);

    // ---------------- Phase 1: horizontal lo/hi -> LDS (packed fp16) ----------------
    // Tasks: 22 rows x 28 col-groups of 8 output cols; exactly 4 float4 loads each
    // (window cols c0-3..c0+10); image-edge columns via register mirror-selects.
    for (int task = tid; task < BAND_ROWS * 28; task += 256) {
        const int s  = task / 28;
        const int cg = task - s * 28;
        int r = rbase + s;
        r = (r < 0) ? (-1 - r) : ((r > kH - 1) ? (2 * kH - 1 - r) : r);
        const float* __restrict__ rowp = xp + r * kW;
        const int c0 = cg * 8;

        const float4 A  = *reinterpret_cast<const float4*>(rowp + (cg ? c0 - 4 : 0));
        const float4 B  = *reinterpret_cast<const float4*>(rowp + c0);
        const float4 Cv = *reinterpret_cast<const float4*>(rowp + c0 + 4);
        const float4 D  = *reinterpret_cast<const float4*>(rowp + (cg < 27 ? c0 + 8 : kW - 16));

        float xv[14];  // cols c0-3 .. c0+10
        xv[0]  = cg ? A.y : B.z;          // col -3 -> 2 at left edge
        xv[1]  = cg ? A.z : B.y;          // col -2 -> 1
        xv[2]  = cg ? A.w : B.x;          // col -1 -> 0
        xv[3]  = B.x;  xv[4] = B.y;  xv[5] = B.z;  xv[6] = B.w;
        xv[7]  = Cv.x; xv[8] = Cv.y; xv[9] = Cv.z; xv[10] = Cv.w;
        xv[11] = (cg < 27) ? D.x : Cv.w;  // col 224 -> 223 at right edge
        xv[12] = (cg < 27) ? D.y : Cv.z;  // col 225 -> 222
        xv[13] = (cg < 27) ? D.z : Cv.y;  // col 226 -> 221

        unsigned int pk[8];
        #pragma unroll
        for (int u = 0; u < 8; ++u) {
            const float lo = H0[0] * xv[u + 1] + H0[1] * xv[u + 2] + H0[2] * xv[u + 3]
                           + H0[3] * xv[u + 4] + H0[4] * xv[u + 5];
            const float hi = H1[0] * xv[u + 0] + H1[1] * xv[u + 1] + H1[2] * xv[u + 2]
                           + H1[3] * xv[u + 3] + H1[4] * xv[u + 4] + H1[5] * xv[u + 5]
                           + H1[6] * xv[u + 6];
            __half2 p = __floats2half2_rn(lo, hi);
            pk[u] = __builtin_bit_cast(unsigned int, p);
        }
        *reinterpret_cast<uint4*>(&sLH[s][c0])     = make_uint4(pk[0], pk[1], pk[2], pk[3]);
        *reinterpret_cast<uint4*>(&sLH[s][c0 + 4]) = make_uint4(pk[4], pk[5], pk[6], pk[7]);
    }
    __syncthreads();

    // ---------------- Phase 2: 2 output pixels per thread, immediate stores ----------------
    const int n = ch / kC;
    const int c = ch - n * kC;
    const size_t plane   = (size_t)kOH * kOW;      // 12544
    const size_t ostride = (size_t)kC * plane;     // orientation stride in output
    float* __restrict__ outp = out + ((size_t)n * 7 * kC + c) * plane;

    // Tasks: 8 rows x 56 pixel-pairs = 448.
    for (int task = tid; task < R_OUT * 56; task += 256) {
        const int ii = task / 56;                  // 0..7
        const int jp = task - ii * 56;             // pixel pair: j0=2jp, j1=2jp+1
        const int s1 = 2 * ii + 3;                 // LDS row of image row 2*(i0+ii)

        Acc A0, A1;
        acc_init(A0);
        acc_init(A1);

        #pragma unroll
        for (int k = 0; k < 8; ++k) {
            // Window cols 4jp..4jp+3 ({lo,hi} packed): one 16B LDS read.
            const uint4 w4 = *reinterpret_cast<const uint4*>(&sLH[s1 - 3 + k][4 * jp]);
            float lo00, hi00, lo01, hi01, lo10, hi10, lo11, hi11;
            unpack2(w4.x, lo00, hi00);             // col 4jp   (pixel0 even col)
            unpack2(w4.y, lo01, hi01);             // col 4jp+1 (pixel0 odd col)
            unpack2(w4.z, lo10, hi10);             // col 4jp+2 (pixel1 even col)
            unpack2(w4.w, lo11, hi11);             // col 4jp+3 (pixel1 odd col)
            acc_step(A0, k, lo00, hi00, lo01, hi01);
            acc_step(A1, k, lo10, hi10, lo11, hi11);
        }

        const float llp0 = fmaxf(fmaxf(A0.ll_a, A0.ll_b), fmaxf(A0.ll_c, A0.ll_d));
        const float llp1 = fmaxf(fmaxf(A1.ll_a, A1.ll_b), fmaxf(A1.ll_c, A1.ll_d));

        // q2c magnitudes (sqrt(1/2) pre-folded into vertical taps).
        // a=even/even, b=even/odd, c=odd/even, d=odd/odd
        const float m15_0  = magf(A0.lh_a - A0.lh_d, A0.lh_b + A0.lh_c);
        const float m165_0 = magf(A0.lh_a + A0.lh_d, A0.lh_b - A0.lh_c);
        const float m45_0  = magf(A0.hh_a - A0.hh_d, A0.hh_b + A0.hh_c);
        const float m135_0 = magf(A0.hh_a + A0.hh_d, A0.hh_b - A0.hh_c);
        const float m75_0  = magf(A0.hl_a - A0.hl_d, A0.hl_b + A0.hl_c);
        const float m105_0 = magf(A0.hl_a + A0.hl_d, A0.hl_b - A0.hl_c);

        const float m15_1  = magf(A1.lh_a - A1.lh_d, A1.lh_b + A1.lh_c);
        const float m165_1 = magf(A1.lh_a + A1.lh_d, A1.lh_b - A1.lh_c);
        const float m45_1  = magf(A1.hh_a - A1.hh_d, A1.hh_b + A1.hh_c);
        const float m135_1 = magf(A1.hh_a + A1.hh_d, A1.hh_b - A1.hh_c);
        const float m75_1  = magf(A1.hl_a - A1.hl_d, A1.hl_b + A1.hl_c);
        const float m105_1 = magf(A1.hl_a + A1.hl_d, A1.hl_b - A1.hl_c);

        // Immediate nontemporal dwordx2 stores (write-once data).
        const size_t pix = (size_t)(i0 + ii) * kOW + 2 * jp;
        nt_store2(outp + pix,               llp0,   llp1);
        nt_store2(outp + ostride     + pix, m15_0,  m15_1);
        nt_store2(outp + 2 * ostride + pix, m45_0,  m45_1);
        nt_store2(outp + 3 * ostride + pix, m75_0,  m75_1);
        nt_store2(outp + 4 * ostride + pix, m105_0, m105_1);
        nt_store2(outp + 5 * ostride + pix, m135_0, m135_1);
        nt_store2(outp + 6 * ostride + pix, m165_0, m165_1);
    }
}

extern "C" void kernel_launch(void* const* d_in, const int* in_sizes, int n_in,
                              void* d_out, int out_size, void* d_ws, size_t ws_size,
                              hipStream_t stream) {
    const float* x = (const float*)d_in[0];
    float* out = (float*)d_out;
    scat_fused_kernel<<<kGrid, 256, 0, stream>>>(x, out);
}

// Round 8
// 95.635 us; speedup vs baseline: 1.5899x; 1.1721x over previous
//
#include <hip/hip_runtime.h>
#include <hip/hip_fp16.h>
#include <math.h>

namespace {
constexpr int kN = 16, kC = 64, kH = 224, kW = 224;
constexpr int kOH = kH / 2, kOW = kW / 2;          // 112 x 112
constexpr int R_OUT = 8;                           // output rows per block
constexpr int BAND_ROWS = 2 * R_OUT + 6;           // 22 lo/hi rows (halo 3 each side)
constexpr int NBANDS = kOH / R_OUT;                // 14
constexpr int PADW = kW + 4;                       // row pad (bank spread); 912B rows
constexpr int kGrid = kN * kC * NBANDS;            // 14336 (multiple of 8)
constexpr int kChunk = kGrid / 8;                  // 1792 blocks per XCD
constexpr float kMagBias = 0.01f;
constexpr float kMB2 = kMagBias * kMagBias;
constexpr double kSqrtHalf = 0.7071067811865476;

// Horizontal taps (plain, f32 math in phase 1).
constexpr float H0[5] = {-0.05f, 0.25f, 0.6f, 0.25f, -0.05f};
constexpr float H1[7] = {-0.0107142857142857f, 0.0535714285714286f,
                          0.2607142857142857f, -0.6071428571428571f,
                          0.2607142857142857f, 0.0535714285714286f,
                         -0.0107142857142857f};

// --- compile-time float -> fp16 bits (values are all normal; RN, ties-away) ---
constexpr unsigned short f2h(double x) {
    unsigned short s = 0;
    if (x < 0) { s = 0x8000; x = -x; }
    if (x == 0.0) return s;
    int e = 0;
    while (x >= 2.0) { x *= 0.5; ++e; }
    while (x < 1.0)  { x *= 2.0; --e; }
    int mi = (int)((x - 1.0) * 1024.0 + 0.5);
    if (mi == 1024) { mi = 0; ++e; }
    return (unsigned short)(s | ((e + 15) << 10) | mi);
}
constexpr unsigned pack2h(double lo, double hi) {
    return (unsigned)f2h(lo) | ((unsigned)f2h(hi) << 16);
}

// Packed vertical taps. T1[k] = {H1[k]*sqrt(1/2)} in both halves (lh | hh).
// T0[t] = {H0[t] (plain, for ll/pool) | H0[t]*sqrt(1/2) (for hl)}.
constexpr double dH1[7] = {-0.0107142857142857, 0.0535714285714286,
                            0.2607142857142857, -0.6071428571428571,
                            0.2607142857142857, 0.0535714285714286,
                           -0.0107142857142857};
constexpr double dH0[5] = {-0.05, 0.25, 0.6, 0.25, -0.05};
constexpr unsigned T1[7] = {
    pack2h(dH1[0] * kSqrtHalf, dH1[0] * kSqrtHalf),
    pack2h(dH1[1] * kSqrtHalf, dH1[1] * kSqrtHalf),
    pack2h(dH1[2] * kSqrtHalf, dH1[2] * kSqrtHalf),
    pack2h(dH1[3] * kSqrtHalf, dH1[3] * kSqrtHalf),
    pack2h(dH1[4] * kSqrtHalf, dH1[4] * kSqrtHalf),
    pack2h(dH1[5] * kSqrtHalf, dH1[5] * kSqrtHalf),
    pack2h(dH1[6] * kSqrtHalf, dH1[6] * kSqrtHalf)};
constexpr unsigned T0[5] = {
    pack2h(dH0[0], dH0[0] * kSqrtHalf),
    pack2h(dH0[1], dH0[1] * kSqrtHalf),
    pack2h(dH0[2], dH0[2] * kSqrtHalf),
    pack2h(dH0[3], dH0[3] * kSqrtHalf),
    pack2h(dH0[4], dH0[4] * kSqrtHalf)};
}  // namespace

typedef float v2f __attribute__((ext_vector_type(2)));

__device__ __forceinline__ float magf(float re, float im) {
    return __builtin_amdgcn_sqrtf(fmaf(re, re, fmaf(im, im, kMB2))) - kMagBias;
}

__device__ __forceinline__ void unpack2(__half2 h, float& a, float& b) {
    a = __low2float(h);
    b = __high2float(h);
}

__device__ __forceinline__ void nt_store2(float* p, float a, float b) {
    v2f v; v.x = a; v.y = b;
    __builtin_nontemporal_store(v, reinterpret_cast<v2f*>(p));
}

__device__ __forceinline__ __half2 h2c(unsigned bits) {
    return __builtin_bit_cast(__half2, bits);
}

__global__ __launch_bounds__(256, 8)
void scat_fused_kernel(const float* __restrict__ x, float* __restrict__ out) {
    // Packed horizontal filter outputs: per (row, col) a __half2 {lo, hi}.
    __shared__ __half2 sLH[BAND_ROWS][PADW];       // 22*228*4 = 20,064 B -> 8 blocks/CU

    // XCD-aware bijective swizzle: adjacent logical bands share an XCD's L2.
    const int phys = blockIdx.x;
    const int b    = (phys & 7) * kChunk + (phys >> 3);

    const int band = b % NBANDS;
    const int ch   = b / NBANDS;                   // n*kC + c
    const int i0   = band * R_OUT;                 // first output row of band
    const int rbase = 2 * i0 - 3;                  // first lo/hi image row (may be <0)
    const int tid  = threadIdx.x;

    const float* __restrict__ xp = x + (size_t)ch * (kH * kW);

    // ---------------- Phase 1: horizontal lo/hi -> LDS (packed fp16) ----------------
    // Tasks: 22 rows x 28 col-groups of 8 output cols; exactly 4 float4 loads each
    // (window cols c0-3..c0+10); image-edge columns via register mirror-selects.
    for (int task = tid; task < BAND_ROWS * 28; task += 256) {
        const int s  = task / 28;
        const int cg = task - s * 28;
        int r = rbase + s;
        r = (r < 0) ? (-1 - r) : ((r > kH - 1) ? (2 * kH - 1 - r) : r);
        const float* __restrict__ rowp = xp + r * kW;
        const int c0 = cg * 8;

        const float4 A  = *reinterpret_cast<const float4*>(rowp + (cg ? c0 - 4 : 0));
        const float4 B  = *reinterpret_cast<const float4*>(rowp + c0);
        const float4 Cv = *reinterpret_cast<const float4*>(rowp + c0 + 4);
        const float4 D  = *reinterpret_cast<const float4*>(rowp + (cg < 27 ? c0 + 8 : kW - 16));

        float xv[14];  // cols c0-3 .. c0+10
        xv[0]  = cg ? A.y : B.z;          // col -3 -> 2 at left edge
        xv[1]  = cg ? A.z : B.y;          // col -2 -> 1
        xv[2]  = cg ? A.w : B.x;          // col -1 -> 0
        xv[3]  = B.x;  xv[4] = B.y;  xv[5] = B.z;  xv[6] = B.w;
        xv[7]  = Cv.x; xv[8] = Cv.y; xv[9] = Cv.z; xv[10] = Cv.w;
        xv[11] = (cg < 27) ? D.x : Cv.w;  // col 224 -> 223 at right edge
        xv[12] = (cg < 27) ? D.y : Cv.z;  // col 225 -> 222
        xv[13] = (cg < 27) ? D.z : Cv.y;  // col 226 -> 221

        unsigned int pk[8];
        #pragma unroll
        for (int u = 0; u < 8; ++u) {
            const float lo = H0[0] * xv[u + 1] + H0[1] * xv[u + 2] + H0[2] * xv[u + 3]
                           + H0[3] * xv[u + 4] + H0[4] * xv[u + 5];
            const float hi = H1[0] * xv[u + 0] + H1[1] * xv[u + 1] + H1[2] * xv[u + 2]
                           + H1[3] * xv[u + 3] + H1[4] * xv[u + 4] + H1[5] * xv[u + 5]
                           + H1[6] * xv[u + 6];
            __half2 p = __floats2half2_rn(lo, hi);
            pk[u] = __builtin_bit_cast(unsigned int, p);
        }
        *reinterpret_cast<uint4*>(&sLH[s][c0])     = make_uint4(pk[0], pk[1], pk[2], pk[3]);
        *reinterpret_cast<uint4*>(&sLH[s][c0 + 4]) = make_uint4(pk[4], pk[5], pk[6], pk[7]);
    }
    __syncthreads();

    // ---------------- Phase 2: packed-fp16 vertical filters (v_pk_fma_f16) ----------------
    const int n = ch / kC;
    const int c = ch - n * kC;
    const size_t plane   = (size_t)kOH * kOW;      // 12544
    const size_t ostride = (size_t)kC * plane;     // orientation stride in output
    float* __restrict__ outp = out + ((size_t)n * 7 * kC + c) * plane;

    // Tasks: 8 rows x 56 pixel-pairs = 448.
    for (int task = tid; task < R_OUT * 56; task += 256) {
        const int ii = task / 56;                  // 0..7
        const int jp = task - ii * 56;             // pixel pair: j0=2jp, j1=2jp+1
        const int s1 = 2 * ii + 3;                 // LDS row of image row 2*(i0+ii)

        // Packed accumulators {lo-branch | hi-branch}:
        //   LHH[i] = {lh_i, hh_i}, LLHL[i] = {ll_i, hl_i};
        //   i: 0=a(even row,even col) 1=b(even,odd) 2=c(odd,even) 3=d(odd,odd)
        const __half2 z = h2c(0u);
        __half2 A_lhh[4]  = {z, z, z, z}, A_llhl[4] = {z, z, z, z};
        __half2 B_lhh[4]  = {z, z, z, z}, B_llhl[4] = {z, z, z, z};

        #pragma unroll
        for (int k = 0; k < 8; ++k) {
            // Window cols 4jp..4jp+3 ({lo,hi} packed): one 16B LDS read.
            const uint4 w4 = *reinterpret_cast<const uint4*>(&sLH[s1 - 3 + k][4 * jp]);
            const __half2 c0 = h2c(w4.x);          // px0 even col
            const __half2 c1 = h2c(w4.y);          // px0 odd col
            const __half2 c2 = h2c(w4.z);          // px1 even col
            const __half2 c3 = h2c(w4.w);          // px1 odd col

            if (k <= 6) {                          // 7-tap, even output row
                const __half2 t = h2c(T1[k]);
                A_lhh[0] = __hfma2(t, c0, A_lhh[0]);
                A_lhh[1] = __hfma2(t, c1, A_lhh[1]);
                B_lhh[0] = __hfma2(t, c2, B_lhh[0]);
                B_lhh[1] = __hfma2(t, c3, B_lhh[1]);
            }
            if (k >= 1) {                          // 7-tap, odd output row
                const __half2 t = h2c(T1[k - 1]);
                A_lhh[2] = __hfma2(t, c0, A_lhh[2]);
                A_lhh[3] = __hfma2(t, c1, A_lhh[3]);
                B_lhh[2] = __hfma2(t, c2, B_lhh[2]);
                B_lhh[3] = __hfma2(t, c3, B_lhh[3]);
            }
            if (k >= 1 && k <= 5) {                // 5-tap, even output row
                const __half2 t = h2c(T0[k - 1]);
                A_llhl[0] = __hfma2(t, c0, A_llhl[0]);
                A_llhl[1] = __hfma2(t, c1, A_llhl[1]);
                B_llhl[0] = __hfma2(t, c2, B_llhl[0]);
                B_llhl[1] = __hfma2(t, c3, B_llhl[1]);
            }
            if (k >= 2 && k <= 6) {                // 5-tap, odd output row
                const __half2 t = h2c(T0[k - 2]);
                A_llhl[2] = __hfma2(t, c0, A_llhl[2]);
                A_llhl[3] = __hfma2(t, c1, A_llhl[3]);
                B_llhl[2] = __hfma2(t, c2, B_llhl[2]);
                B_llhl[3] = __hfma2(t, c3, B_llhl[3]);
            }
        }

        // Epilogue: unpack once, pool + q2c + magnitudes in f32.
        float lh_a, hh_a, lh_b, hh_b, lh_c, hh_c, lh_d, hh_d;
        float ll_a, hl_a, ll_b, hl_b, ll_c, hl_c, ll_d, hl_d;

        unpack2(A_lhh[0], lh_a, hh_a);  unpack2(A_lhh[1], lh_b, hh_b);
        unpack2(A_lhh[2], lh_c, hh_c);  unpack2(A_lhh[3], lh_d, hh_d);
        unpack2(A_llhl[0], ll_a, hl_a); unpack2(A_llhl[1], ll_b, hl_b);
        unpack2(A_llhl[2], ll_c, hl_c); unpack2(A_llhl[3], ll_d, hl_d);

        const float llp0   = fmaxf(fmaxf(ll_a, ll_b), fmaxf(ll_c, ll_d));
        const float m15_0  = magf(lh_a - lh_d, lh_b + lh_c);
        const float m165_0 = magf(lh_a + lh_d, lh_b - lh_c);
        const float m45_0  = magf(hh_a - hh_d, hh_b + hh_c);
        const float m135_0 = magf(hh_a + hh_d, hh_b - hh_c);
        const float m75_0  = magf(hl_a - hl_d, hl_b + hl_c);
        const float m105_0 = magf(hl_a + hl_d, hl_b - hl_c);

        unpack2(B_lhh[0], lh_a, hh_a);  unpack2(B_lhh[1], lh_b, hh_b);
        unpack2(B_lhh[2], lh_c, hh_c);  unpack2(B_lhh[3], lh_d, hh_d);
        unpack2(B_llhl[0], ll_a, hl_a); unpack2(B_llhl[1], ll_b, hl_b);
        unpack2(B_llhl[2], ll_c, hl_c); unpack2(B_llhl[3], ll_d, hl_d);

        const float llp1   = fmaxf(fmaxf(ll_a, ll_b), fmaxf(ll_c, ll_d));
        const float m15_1  = magf(lh_a - lh_d, lh_b + lh_c);
        const float m165_1 = magf(lh_a + lh_d, lh_b - lh_c);
        const float m45_1  = magf(hh_a - hh_d, hh_b + hh_c);
        const float m135_1 = magf(hh_a + hh_d, hh_b - hh_c);
        const float m75_1  = magf(hl_a - hl_d, hl_b + hl_c);
        const float m105_1 = magf(hl_a + hl_d, hl_b - hl_c);

        // Immediate nontemporal dwordx2 stores (write-once data).
        const size_t pix = (size_t)(i0 + ii) * kOW + 2 * jp;
        nt_store2(outp + pix,               llp0,   llp1);
        nt_store2(outp + ostride     + pix, m15_0,  m15_1);
        nt_store2(outp + 2 * ostride + pix, m45_0,  m45_1);
        nt_store2(outp + 3 * ostride + pix, m75_0,  m75_1);
        nt_store2(outp + 4 * ostride + pix, m105_0, m105_1);
        nt_store2(outp + 5 * ostride + pix, m135_0, m135_1);
        nt_store2(outp + 6 * ostride + pix, m165_0, m165_1);
    }
}

extern "C" void kernel_launch(void* const* d_in, const int* in_sizes, int n_in,
                              void* d_out, int out_size, void* d_ws, size_t ws_size,
                              hipStream_t stream) {
    const float* x = (const float*)d_in[0];
    float* out = (float*)d_out;
    scat_fused_kernel<<<kGrid, 256, 0, stream>>>(x, out);
}